// Round 6
// baseline (253.668 us; speedup 1.0000x reference)
//
#include <hip/hip_runtime.h>
#include <math.h>

typedef float nfloat4 __attribute__((ext_vector_type(4)));

// ---------------------------------------------------------------------------
// Fused kernel. Block roles (interleaved so both kinds are co-resident/CU):
//   role EW  : relu_out = max(x + reco, 0)      (grid-stride float4 streams)
//   role PROJ: cone projection sampling (x+reco) on the fly (TWO=1 semantics)
// The fp32 add x[i]+reco[i] is bit-identical to the staged 'upd' volume, so
// fusing removes the 64 MiB staging write AND the inter-kernel serialization:
// HBM-streaming EW blocks overlap with latency-bound gather PROJ blocks.
// ---------------------------------------------------------------------------

__device__ __forceinline__ float fetch_corner2(
    const float* __restrict__ vol_a,
    const float* __restrict__ vol_b,
    int ix, int iy, int iz,
    int nx, int ny, int nz)
{
    bool valid = (ix >= 0) & (ix < nx) & (iy >= 0) & (iy < ny) &
                 (iz >= 0) & (iz < nz);
    if (!valid) return 0.0f;
    int idx = (ix * ny + iy) * nz + iz;
    return vol_a[idx] + vol_b[idx];
}

__device__ __forceinline__ void clip_axis(float a, float b, float lo, float hi,
                                          float& t_lo, float& t_hi)
{
    if (fabsf(b) > 1e-6f) {
        float t0 = (lo - a) / b;
        float t1 = (hi - a) / b;
        float tmn = fminf(t0, t1);
        float tmx = fmaxf(t0, t1);
        t_lo = fmaxf(t_lo, tmn);
        t_hi = fminf(t_hi, tmx);
    } else {
        if (a <= lo || a >= hi) { t_lo = 1.0f; t_hi = 0.0f; }
    }
}

__global__ __launch_bounds__(256) void fused_kernel(
    const float* __restrict__ x,
    const float* __restrict__ reco,
    const float* __restrict__ src_pos,
    const float* __restrict__ det_center,
    const float* __restrict__ det_u_vec,
    const float* __restrict__ det_v_vec,
    const float* __restrict__ du_p,
    const float* __restrict__ dv_p,
    const float* __restrict__ spacing_p,
    const int* __restrict__ det_u_p,
    const int* __restrict__ det_v_p,
    const int* __restrict__ nsteps_p,
    float* __restrict__ sino,
    float* __restrict__ relu_out,
    int n4,            // float4 count of volume
    int ew_blocks,     // number of EW-role blocks
    int n_views, int nx, int ny, int nz)
{
    const int b = blockIdx.x;
    const int total_b = gridDim.x;
    // Proportional interleave: ew_before = #EW blocks among [0, b)
    const long ew_before = ((long)b * ew_blocks) / total_b;
    const bool is_ew = (((long)(b + 1) * ew_blocks) / total_b) > ew_before;

    if (is_ew) {
        // ---------------- EW role: add + relu (proven R2 loop) ----------------
        const int ew_id = (int)ew_before;
        const nfloat4* x4 = (const nfloat4*)x;
        const nfloat4* r4 = (const nfloat4*)reco;
        nfloat4* ro4 = (nfloat4*)relu_out;
        int i = ew_id * 256 + threadIdx.x;
        const int stride = ew_blocks * 256;
        for (; i < n4; i += stride) {
            nfloat4 a = x4[i];
            nfloat4 c = r4[i];
            nfloat4 u = a + c;
            nfloat4 r;
            r.x = fmaxf(u.x, 0.f); r.y = fmaxf(u.y, 0.f);
            r.z = fmaxf(u.z, 0.f); r.w = fmaxf(u.w, 0.f);
            ro4[i] = r;
        }
        return;
    }

    // ---------------- PROJ role: 32 pixels x 8 segments ----------------
    const int pb = (int)(b - ew_before);   // proj block id

    const int det_u = *det_u_p;
    const int det_v = *det_v_p;
    const int n_steps = *nsteps_p;
    const float du = *du_p;
    const float dv = *dv_p;
    const float inv_sp = 1.0f / *spacing_p;

    const long total = (long)n_views * det_u * det_v;
    const int pix = threadIdx.x & 31;
    const int seg = threadIdx.x >> 5;   // 0..7
    const long idx = (long)pb * 32 + pix;
    const bool live = idx < total;

    const long cidx = live ? idx : 0;
    const int v = (int)(cidx % det_v);
    const int u = (int)((cidx / det_v) % det_u);
    const int view = (int)(cidx / ((long)det_u * det_v));

    const float us = ((float)u - (det_u - 1) * 0.5f) * du;
    const float vs = ((float)v - (det_v - 1) * 0.5f) * dv;

    const float sx = src_pos[view * 3 + 0];
    const float sy = src_pos[view * 3 + 1];
    const float sz = src_pos[view * 3 + 2];

    const float dpx = det_center[view * 3 + 0] + us * det_u_vec[view * 3 + 0] + vs * det_v_vec[view * 3 + 0];
    const float dpy = det_center[view * 3 + 1] + us * det_u_vec[view * 3 + 1] + vs * det_v_vec[view * 3 + 1];
    const float dpz = det_center[view * 3 + 2] + us * det_u_vec[view * 3 + 2] + vs * det_v_vec[view * 3 + 2];

    const float dx = dpx - sx;
    const float dy = dpy - sy;
    const float dz = dpz - sz;
    const float ray_len = sqrtf(dx * dx + dy * dy + dz * dz);
    const float step_len = ray_len / (float)n_steps;

    const float cx = (nx - 1) * 0.5f;
    const float cy = (ny - 1) * 0.5f;
    const float cz = (nz - 1) * 0.5f;

    // clip s-range so voxel coords stay in (-1, N); widened below for fp safety
    float t_lo = 0.0f, t_hi = 1.0f;
    clip_axis(sx * inv_sp + cx, dx * inv_sp, -1.0f, (float)nx, t_lo, t_hi);
    clip_axis(sy * inv_sp + cy, dy * inv_sp, -1.0f, (float)ny, t_lo, t_hi);
    clip_axis(sz * inv_sp + cz, dz * inv_sp, -1.0f, (float)nz, t_lo, t_hi);

    int i_min = 0, i_max = -1;
    if (t_hi > t_lo) {
        i_min = (int)floorf(t_lo * (float)n_steps - 0.5f) - 1;
        i_max = (int)ceilf(t_hi * (float)n_steps - 0.5f) + 1;
        i_min = max(i_min, 0);
        i_max = min(i_max, n_steps - 1);
    }
    if (!live) { i_min = 0; i_max = -1; }

    // distribute [i_min, i_max] across 8 segments
    const int count = i_max - i_min + 1;
    const int per = (count + 7) >> 3;
    const int is = i_min + seg * per;
    const int ie = min(is + per - 1, i_max);

    const float inv_n = 1.0f / (float)n_steps;

    float acc = 0.0f;
    for (int i = is; i <= ie; ++i) {
        const float s = ((float)i + 0.5f) * inv_n;
        const float px = fmaf(s, dx, sx) * inv_sp + cx;
        const float py = fmaf(s, dy, sy) * inv_sp + cy;
        const float pz = fmaf(s, dz, sz) * inv_sp + cz;

        const float x0f = floorf(px);
        const float y0f = floorf(py);
        const float z0f = floorf(pz);
        const float fx = px - x0f;
        const float fy = py - y0f;
        const float fz = pz - z0f;
        const int x0 = (int)x0f;
        const int y0 = (int)y0f;
        const int z0 = (int)z0f;

        const float gx = 1.0f - fx;
        const float gy = 1.0f - fy;
        const float gz = 1.0f - fz;

        const bool interior = (x0 >= 0) & (x0 + 1 < nx) &
                              (y0 >= 0) & (y0 + 1 < ny) &
                              (z0 >= 0) & (z0 + 1 < nz);

        float samp = 0.0f;
        if (interior) {
            const int base = (x0 * ny + y0) * nz + z0;
            const float* pa = x + base;
            const float* pc = reco + base;
            const float v000 = pa[0]            + pc[0];
            const float v001 = pa[1]            + pc[1];
            const float v010 = pa[nz]           + pc[nz];
            const float v011 = pa[nz + 1]       + pc[nz + 1];
            const float v100 = pa[ny * nz]      + pc[ny * nz];
            const float v101 = pa[ny * nz + 1]  + pc[ny * nz + 1];
            const float v110 = pa[ny * nz + nz] + pc[ny * nz + nz];
            const float v111 = pa[ny * nz + nz + 1] + pc[ny * nz + nz + 1];
            samp = fmaf(gx * gy * gz, v000, samp);
            samp = fmaf(gx * gy * fz, v001, samp);
            samp = fmaf(gx * fy * gz, v010, samp);
            samp = fmaf(gx * fy * fz, v011, samp);
            samp = fmaf(fx * gy * gz, v100, samp);
            samp = fmaf(fx * gy * fz, v101, samp);
            samp = fmaf(fx * fy * gz, v110, samp);
            samp = fmaf(fx * fy * fz, v111, samp);
        } else {
            samp = fmaf(gx * gy * gz, fetch_corner2(x, reco, x0,     y0,     z0,     nx, ny, nz), samp);
            samp = fmaf(gx * gy * fz, fetch_corner2(x, reco, x0,     y0,     z0 + 1, nx, ny, nz), samp);
            samp = fmaf(gx * fy * gz, fetch_corner2(x, reco, x0,     y0 + 1, z0,     nx, ny, nz), samp);
            samp = fmaf(gx * fy * fz, fetch_corner2(x, reco, x0,     y0 + 1, z0 + 1, nx, ny, nz), samp);
            samp = fmaf(fx * gy * gz, fetch_corner2(x, reco, x0 + 1, y0,     z0,     nx, ny, nz), samp);
            samp = fmaf(fx * gy * fz, fetch_corner2(x, reco, x0 + 1, y0,     z0 + 1, nx, ny, nz), samp);
            samp = fmaf(fx * fy * gz, fetch_corner2(x, reco, x0 + 1, y0 + 1, z0,     nx, ny, nz), samp);
            samp = fmaf(fx * fy * fz, fetch_corner2(x, reco, x0 + 1, y0 + 1, z0 + 1, nx, ny, nz), samp);
        }
        acc += samp;
    }

    // reduce 8 segments per pixel through LDS
    __shared__ float red[256];
    red[threadIdx.x] = acc;
    __syncthreads();
    if (seg == 0 && live) {
        float tot = red[pix]       + red[pix + 32]  + red[pix + 64]  + red[pix + 96] +
                    red[pix + 128] + red[pix + 160] + red[pix + 192] + red[pix + 224];
        sino[idx] = tot * step_len;
    }
}

extern "C" void kernel_launch(void* const* d_in, const int* in_sizes, int n_in,
                              void* d_out, int out_size, void* d_ws, size_t ws_size,
                              hipStream_t stream) {
    const float* x          = (const float*)d_in[0];
    const float* reco       = (const float*)d_in[1];
    const float* src_pos    = (const float*)d_in[2];
    const float* det_center = (const float*)d_in[3];
    const float* det_u_vec  = (const float*)d_in[4];
    const float* det_v_vec  = (const float*)d_in[5];
    const float* du_p       = (const float*)d_in[6];
    const float* dv_p       = (const float*)d_in[7];
    const float* spacing_p  = (const float*)d_in[8];
    const int*   det_u_p    = (const int*)d_in[9];
    const int*   det_v_p    = (const int*)d_in[10];
    const int*   nsteps_p   = (const int*)d_in[11];

    const int n_vol = in_sizes[0];          // 256^3
    const int n_views = in_sizes[2] / 3;    // 8

    int n = 1;
    while ((long)(n + 1) * (n + 1) * (n + 1) <= (long)n_vol) ++n;
    const int nx = n, ny = n, nz = n;

    const int sino_size = out_size - n_vol;  // 8*128*128
    float* sino     = (float*)d_out;
    float* relu_out = (float*)d_out + sino_size;

    const int n4 = n_vol / 4;                      // float4 count
    const int ew_blocks   = 2048;                  // proven streaming config
    const int proj_blocks = (sino_size + 31) / 32; // 32 pixels per block
    const int total_blocks = ew_blocks + proj_blocks;

    fused_kernel<<<total_blocks, 256, 0, stream>>>(
        x, reco,
        src_pos, det_center, det_u_vec, det_v_vec,
        du_p, dv_p, spacing_p, det_u_p, det_v_p, nsteps_p,
        sino, relu_out,
        n4, ew_blocks, n_views, nx, ny, nz);
}

// Round 7
// 236.972 us; speedup vs baseline: 1.0705x; 1.0705x over previous
//
#include <hip/hip_runtime.h>
#include <math.h>

typedef float nfloat4 __attribute__((ext_vector_type(4)));

// ---------------------------------------------------------------------------
// Kernel 1: updated = x + reco; relu_out = max(updated,0); upd_out = updated.
// Exact R2 structure (simple grid-stride float4, 2048 blocks) — measured
// 72 us; the R5 4-way strided-ILP variant regressed to ~80 us (DRAM
// locality), and nontemporal builtins broke harness restore coherence (R4).
// ---------------------------------------------------------------------------
__global__ __launch_bounds__(256) void add_relu_kernel(
    const float* __restrict__ x,
    const float* __restrict__ reco,
    float* __restrict__ relu_out,
    float* __restrict__ upd_out,
    int n4)
{
    int i = blockIdx.x * blockDim.x + threadIdx.x;
    int stride = gridDim.x * blockDim.x;
    const nfloat4* x4 = (const nfloat4*)x;
    const nfloat4* r4 = (const nfloat4*)reco;
    nfloat4* ro4 = (nfloat4*)relu_out;
    nfloat4* uo4 = (nfloat4*)upd_out;
    for (; i < n4; i += stride) {
        nfloat4 a = x4[i];
        nfloat4 b = r4[i];
        nfloat4 u = a + b;
        if (uo4) uo4[i] = u;
        nfloat4 r;
        r.x = fmaxf(u.x, 0.f); r.y = fmaxf(u.y, 0.f);
        r.z = fmaxf(u.z, 0.f); r.w = fmaxf(u.w, 0.f);
        ro4[i] = r;
    }
}

// ---------------------------------------------------------------------------
// Corner fetch with zero-outside semantics (matches reference clip+mask).
// ---------------------------------------------------------------------------
template <int TWO>
__device__ __forceinline__ float fetch_corner(
    const float* __restrict__ vol_a,
    const float* __restrict__ vol_b,
    int ix, int iy, int iz,
    int nx, int ny, int nz)
{
    bool valid = (ix >= 0) & (ix < nx) & (iy >= 0) & (iy < ny) &
                 (iz >= 0) & (iz < nz);
    if (!valid) return 0.0f;
    int idx = (ix * ny + iy) * nz + iz;
    float v = vol_a[idx];
    if (TWO) v += vol_b[idx];
    return v;
}

__device__ __forceinline__ void clip_axis(float a, float b, float lo, float hi,
                                          float& t_lo, float& t_hi)
{
    if (fabsf(b) > 1e-6f) {
        float t0 = (lo - a) / b;
        float t1 = (hi - a) / b;
        float tmn = fminf(t0, t1);
        float tmx = fmaxf(t0, t1);
        t_lo = fmaxf(t_lo, tmn);
        t_hi = fminf(t_hi, tmx);
    } else {
        if (a <= lo || a >= hi) { t_lo = 1.0f; t_hi = 0.0f; }
    }
}

// ---------------------------------------------------------------------------
// Kernel 2: cone projection. 64 consecutive-v pixels (lane) x 4 segments
// (one WAVE per segment) per 256-thread block: every wave's 64 lanes are
// 64 consecutive v of the same (view,u) and the same segment, so the 8
// corner gathers per step are contiguous z-runs (coalesced). Interior cells
// take an unchecked fast path with identical fmaf ordering (bit-identical).
// Ray clipped to the volume slab (widened; boundary path keeps per-corner
// checks so clipping precision cannot affect correctness).
// ---------------------------------------------------------------------------
template <int TWO>
__global__ __launch_bounds__(256) void cone_project_seg_kernel(
    const float* __restrict__ vol_a,
    const float* __restrict__ vol_b,
    const float* __restrict__ src_pos,
    const float* __restrict__ det_center,
    const float* __restrict__ det_u_vec,
    const float* __restrict__ det_v_vec,
    const float* __restrict__ du_p,
    const float* __restrict__ dv_p,
    const float* __restrict__ spacing_p,
    const int* __restrict__ det_u_p,
    const int* __restrict__ det_v_p,
    const int* __restrict__ nsteps_p,
    float* __restrict__ sino,
    int n_views, int nx, int ny, int nz)
{
    const int det_u = *det_u_p;
    const int det_v = *det_v_p;
    const int n_steps = *nsteps_p;
    const float du = *du_p;
    const float dv = *dv_p;
    const float inv_sp = 1.0f / *spacing_p;

    const long total = (long)n_views * det_u * det_v;
    const int pix = threadIdx.x & 63;   // lane: consecutive v
    const int seg = threadIdx.x >> 6;   // wave id: 0..3
    const long idx = (long)blockIdx.x * 64 + pix;
    const bool live = idx < total;

    const long cidx = live ? idx : 0;
    const int v = (int)(cidx % det_v);
    const int u = (int)((cidx / det_v) % det_u);
    const int view = (int)(cidx / ((long)det_u * det_v));

    const float us = ((float)u - (det_u - 1) * 0.5f) * du;
    const float vs = ((float)v - (det_v - 1) * 0.5f) * dv;

    const float sx = src_pos[view * 3 + 0];
    const float sy = src_pos[view * 3 + 1];
    const float sz = src_pos[view * 3 + 2];

    const float dpx = det_center[view * 3 + 0] + us * det_u_vec[view * 3 + 0] + vs * det_v_vec[view * 3 + 0];
    const float dpy = det_center[view * 3 + 1] + us * det_u_vec[view * 3 + 1] + vs * det_v_vec[view * 3 + 1];
    const float dpz = det_center[view * 3 + 2] + us * det_u_vec[view * 3 + 2] + vs * det_v_vec[view * 3 + 2];

    const float dx = dpx - sx;
    const float dy = dpy - sy;
    const float dz = dpz - sz;
    const float ray_len = sqrtf(dx * dx + dy * dy + dz * dz);
    const float step_len = ray_len / (float)n_steps;

    const float cx = (nx - 1) * 0.5f;
    const float cy = (ny - 1) * 0.5f;
    const float cz = (nz - 1) * 0.5f;

    // clip s-range so voxel coords stay in (-1, N)
    float t_lo = 0.0f, t_hi = 1.0f;
    clip_axis(sx * inv_sp + cx, dx * inv_sp, -1.0f, (float)nx, t_lo, t_hi);
    clip_axis(sy * inv_sp + cy, dy * inv_sp, -1.0f, (float)ny, t_lo, t_hi);
    clip_axis(sz * inv_sp + cz, dz * inv_sp, -1.0f, (float)nz, t_lo, t_hi);

    int i_min = 0, i_max = -1;
    if (t_hi > t_lo) {
        i_min = (int)floorf(t_lo * (float)n_steps - 0.5f) - 1;
        i_max = (int)ceilf(t_hi * (float)n_steps - 0.5f) + 1;
        i_min = max(i_min, 0);
        i_max = min(i_max, n_steps - 1);
    }
    if (!live) { i_min = 0; i_max = -1; }

    // distribute [i_min, i_max] across 4 segment-waves
    const int count = i_max - i_min + 1;
    const int per = (count + 3) >> 2;
    const int is = i_min + seg * per;
    const int ie = min(is + per - 1, i_max);

    const float inv_n = 1.0f / (float)n_steps;
    const int snz = ny * nz;

    float acc = 0.0f;
    for (int i = is; i <= ie; ++i) {
        const float s = ((float)i + 0.5f) * inv_n;
        const float px = fmaf(s, dx, sx) * inv_sp + cx;
        const float py = fmaf(s, dy, sy) * inv_sp + cy;
        const float pz = fmaf(s, dz, sz) * inv_sp + cz;

        const float x0f = floorf(px);
        const float y0f = floorf(py);
        const float z0f = floorf(pz);
        const float fx = px - x0f;
        const float fy = py - y0f;
        const float fz = pz - z0f;
        const int x0 = (int)x0f;
        const int y0 = (int)y0f;
        const int z0 = (int)z0f;

        const float gx = 1.0f - fx;
        const float gy = 1.0f - fy;
        const float gz = 1.0f - fz;

        const bool interior = (x0 >= 0) & (x0 + 1 < nx) &
                              (y0 >= 0) & (y0 + 1 < ny) &
                              (z0 >= 0) & (z0 + 1 < nz);

        float samp = 0.0f;
        if (interior) {
            const int base = (x0 * ny + y0) * nz + z0;
            const float* pa = vol_a + base;
            float v000 = pa[0];
            float v001 = pa[1];
            float v010 = pa[nz];
            float v011 = pa[nz + 1];
            float v100 = pa[snz];
            float v101 = pa[snz + 1];
            float v110 = pa[snz + nz];
            float v111 = pa[snz + nz + 1];
            if (TWO) {
                const float* pb = vol_b + base;
                v000 += pb[0];
                v001 += pb[1];
                v010 += pb[nz];
                v011 += pb[nz + 1];
                v100 += pb[snz];
                v101 += pb[snz + 1];
                v110 += pb[snz + nz];
                v111 += pb[snz + nz + 1];
            }
            samp = fmaf(gx * gy * gz, v000, samp);
            samp = fmaf(gx * gy * fz, v001, samp);
            samp = fmaf(gx * fy * gz, v010, samp);
            samp = fmaf(gx * fy * fz, v011, samp);
            samp = fmaf(fx * gy * gz, v100, samp);
            samp = fmaf(fx * gy * fz, v101, samp);
            samp = fmaf(fx * fy * gz, v110, samp);
            samp = fmaf(fx * fy * fz, v111, samp);
        } else {
            samp = fmaf(gx * gy * gz, fetch_corner<TWO>(vol_a, vol_b, x0,     y0,     z0,     nx, ny, nz), samp);
            samp = fmaf(gx * gy * fz, fetch_corner<TWO>(vol_a, vol_b, x0,     y0,     z0 + 1, nx, ny, nz), samp);
            samp = fmaf(gx * fy * gz, fetch_corner<TWO>(vol_a, vol_b, x0,     y0 + 1, z0,     nx, ny, nz), samp);
            samp = fmaf(gx * fy * fz, fetch_corner<TWO>(vol_a, vol_b, x0,     y0 + 1, z0 + 1, nx, ny, nz), samp);
            samp = fmaf(fx * gy * gz, fetch_corner<TWO>(vol_a, vol_b, x0 + 1, y0,     z0,     nx, ny, nz), samp);
            samp = fmaf(fx * gy * fz, fetch_corner<TWO>(vol_a, vol_b, x0 + 1, y0,     z0 + 1, nx, ny, nz), samp);
            samp = fmaf(fx * fy * gz, fetch_corner<TWO>(vol_a, vol_b, x0 + 1, y0 + 1, z0,     nx, ny, nz), samp);
            samp = fmaf(fx * fy * fz, fetch_corner<TWO>(vol_a, vol_b, x0 + 1, y0 + 1, z0 + 1, nx, ny, nz), samp);
        }
        acc += samp;
    }

    // reduce 4 segment-waves per pixel through LDS
    __shared__ float red[256];
    red[threadIdx.x] = acc;
    __syncthreads();
    if (seg == 0 && live) {
        float tot = red[pix] + red[pix + 64] + red[pix + 128] + red[pix + 192];
        sino[idx] = tot * step_len;
    }
}

extern "C" void kernel_launch(void* const* d_in, const int* in_sizes, int n_in,
                              void* d_out, int out_size, void* d_ws, size_t ws_size,
                              hipStream_t stream) {
    const float* x          = (const float*)d_in[0];
    const float* reco       = (const float*)d_in[1];
    const float* src_pos    = (const float*)d_in[2];
    const float* det_center = (const float*)d_in[3];
    const float* det_u_vec  = (const float*)d_in[4];
    const float* det_v_vec  = (const float*)d_in[5];
    const float* du_p       = (const float*)d_in[6];
    const float* dv_p       = (const float*)d_in[7];
    const float* spacing_p  = (const float*)d_in[8];
    const int*   det_u_p    = (const int*)d_in[9];
    const int*   det_v_p    = (const int*)d_in[10];
    const int*   nsteps_p   = (const int*)d_in[11];

    const int n_vol = in_sizes[0];          // 256^3
    const int n_views = in_sizes[2] / 3;    // 8

    int n = 1;
    while ((long)(n + 1) * (n + 1) * (n + 1) <= (long)n_vol) ++n;
    const int nx = n, ny = n, nz = n;

    const int sino_size = out_size - n_vol;  // 8*128*128
    float* sino     = (float*)d_out;
    float* relu_out = (float*)d_out + sino_size;

    const bool use_ws = ws_size >= (size_t)n_vol * sizeof(float);
    float* upd = (float*)d_ws;

    // --- Pass 1: elementwise add + relu (+ stage updated volume) ---
    const int n4 = n_vol / 4;
    add_relu_kernel<<<2048, 256, 0, stream>>>(
        x, reco, relu_out, use_ws ? upd : nullptr, n4);

    // --- Pass 2: cone projection (64 v-pixels x 4 segment-waves per block) ---
    const int blocks = (sino_size + 63) / 64;
    if (use_ws) {
        cone_project_seg_kernel<0><<<blocks, 256, 0, stream>>>(
            upd, nullptr,
            src_pos, det_center, det_u_vec, det_v_vec,
            du_p, dv_p, spacing_p, det_u_p, det_v_p, nsteps_p,
            sino, n_views, nx, ny, nz);
    } else {
        cone_project_seg_kernel<1><<<blocks, 256, 0, stream>>>(
            x, reco,
            src_pos, det_center, det_u_vec, det_v_vec,
            du_p, dv_p, spacing_p, det_u_p, det_v_p, nsteps_p,
            sino, n_views, nx, ny, nz);
    }
}